// Round 13
// baseline (71.146 us; speedup 1.0000x reference)
//
#include <hip/hip_runtime.h>
#include <cstdint>

#define B_ 32
#define C_ 2048
#define Q_ 128
#define D_ 128
#define CT 64
#define OFF_ 8.0f
#define NEG_INF_F (-1.0e9f)

typedef __attribute__((ext_vector_type(8))) short bf16x8;
typedef __attribute__((ext_vector_type(4))) float f32x4;

__device__ inline short bf16_rne(float v) {
    unsigned u = __float_as_uint(v);
    return (short)((u + 0x7FFFu + ((u >> 16) & 1u)) >> 16);
}
__device__ inline void split_f32(float v, short& h, short& l) {
    unsigned u  = __float_as_uint(v);
    unsigned hb = u & 0xffff0000u;          // truncated bf16 (hi)
    float lo = v - __uint_as_float(hb);     // exact residual
    h = (short)(hb >> 16);
    l = (short)(__float_as_uint(lo) >> 16);
}

// ---------- prep: qw2e (q.w2 + mask), rne-bf16 of (qry*w3) and qry^T ----------
__global__ __launch_bounds__(256)
void cqa_prep(const float* __restrict__ qry, const float* __restrict__ w,
              const int* __restrict__ qmask, float* __restrict__ qw2e_g,
              unsigned short* __restrict__ qw3Hi, unsigned short* __restrict__ qTHi)
{
    const int b = blockIdx.y, ch = blockIdx.x;   // ch: 16-row chunk of q
    const int t = threadIdx.x;
    const float* qb = qry + (size_t)b * Q_ * D_;

    if (t < 32) {
        int rl = t >> 1, part = t & 1;
        int q = ch * 16 + rl;
        const float* p  = qb + q * D_ + part * 64;
        const float* wp = w + D_ + part * 64;
        float s = 0.f;
        #pragma unroll
        for (int j = 0; j < 64; j += 4) {
            float4 a4 = *(const float4*)(p + j);
            float4 w4 = *(const float4*)(wp + j);
            s += a4.x*w4.x + a4.y*w4.y + a4.z*w4.z + a4.w*w4.w;
        }
        s += __shfl_xor(s, 1, 2);
        if (!part) {
            float madd = (1.0f - (float)qmask[b * Q_ + q]) * NEG_INF_F;
            qw2e_g[b * Q_ + q] = s + madd;
        }
    }
    #pragma unroll
    for (int i = 0; i < 8; ++i) {
        int idx = t + i * 256;            // 16 rows x 128 d
        int ql = idx >> 7, d = idx & 127;
        int q = ch * 16 + ql;
        float v = qb[q * D_ + d];
        qw3Hi[((size_t)b * Q_ + q) * D_ + d] = (unsigned short)bf16_rne(v * w[2 * D_ + d]);
        qTHi[((size_t)b * D_ + d) * Q_ + q]  = (unsigned short)bf16_rne(v);
    }
}

// stage cols [col0,col0+32) of a [128][128]-short row-major matrix into an
// 8KB LDS buffer [128][32] via async DMA (linear LDS dest = base + lane*16B).
__device__ __forceinline__ void stage_b(const unsigned short* __restrict__ gH,
                                        int col0, short* sb, int wv, int lane)
{
    #pragma unroll
    for (int j = 0; j < 2; ++j) {
        int seg = wv * 2 + j;                 // 1KB segment 0..7
        int li  = seg * 64 + lane;            // 16B-unit linear index 0..511
        int row = li >> 2;
        int col = (li & 3) * 8;
        __builtin_amdgcn_global_load_lds(
            (const __attribute__((address_space(1))) void*)(gH + (size_t)row * 128 + col0 + col),
            (__attribute__((address_space(3))) void*)(sb + seg * 512), 16, 0, 0);
    }
}

// ---------- main: G1 (dbuf DMA) + softmax + G2 (reg-A x P-LDS, no staging) ----------
__global__ __launch_bounds__(256, 6)
void cqa_main(const float* __restrict__ ctx, const float* __restrict__ w,
              const float* __restrict__ qw2e_g,
              const unsigned short* __restrict__ qw3Hi, const unsigned short* __restrict__ qTHi,
              float* __restrict__ out, float* __restrict__ part, float* __restrict__ denp_g)
{
    __shared__ __align__(16) char smem[27008];
    short* SB   = (short*)smem;                 // [0,8192): G1 stage buf 0
    short* PHi  = (short*)(smem + 8192);        // [64][136] bf16; first 8KB = G1 buf 1
    float* Tr   = (float*)smem;                 // [32][132] f32 epilogue overlay (16896 B)
    float* red  = (float*)smem;                 // [8][128] f32 overlay (post-Tr)
    float* mlds = (float*)(smem + 25600);       // 64 f32
    float* slds = (float*)(smem + 25856);       // 64 f32 (1/rowsum)
    float* cw1  = (float*)(smem + 26112);       // 64 f32
    float* qw2e = (float*)(smem + 26368);       // 128 f32
    float* dred = (float*)(smem + 26880);       // 8 f32

    const int b   = blockIdx.y;
    const int c0  = blockIdx.x * CT;
    const int tid = threadIdx.x;
    const int lane = tid & 63;
    const int wv   = tid >> 6;
    const int w16  = wv * 16;
    const int lm   = lane & 15;
    const int lg   = lane >> 4;    // 0..3
    const int lk   = lg * 8;       // k-slot start within 32-chunk

    const float* ctxb = ctx + ((size_t)b * C_ + c0) * D_;
    const unsigned short* qw3Hb = qw3Hi + (size_t)b * Q_ * D_;
    const unsigned short* qTHb  = qTHi + (size_t)b * Q_ * D_;

    // kick off DMA of GEMM1 chunk 0 immediately (buf0)
    stage_b(qw3Hb, 0, SB, wv, lane);

    if (tid < Q_) qw2e[tid] = qw2e_g[b * Q_ + tid];

    // A-preload (ctx rows, exact hi/lo split) with fused cw1 = ctx_row . w1
    const float* arow = ctxb + (size_t)(w16 + lm) * D_;
    bf16x8 aHr[4], aLr[4];
    float cws = 0.f;
    #pragma unroll
    for (int t = 0; t < 4; ++t) {
        float4 v0 = *(const float4*)(arow + t * 32 + lk);
        float4 v1 = *(const float4*)(arow + t * 32 + lk + 4);
        float4 w0 = *(const float4*)(w + t * 32 + lk);
        float4 w1v = *(const float4*)(w + t * 32 + lk + 4);
        cws += v0.x*w0.x + v0.y*w0.y + v0.z*w0.z + v0.w*w0.w
             + v1.x*w1v.x + v1.y*w1v.y + v1.z*w1v.z + v1.w*w1v.w;
        float vv[8] = {v0.x, v0.y, v0.z, v0.w, v1.x, v1.y, v1.z, v1.w};
        #pragma unroll
        for (int i = 0; i < 8; ++i) {
            short hh, ll; split_f32(vv[i], hh, ll);
            aHr[t][i] = hh; aLr[t][i] = ll;
        }
    }
    cws += __shfl_xor(cws, 16, 64);
    cws += __shfl_xor(cws, 32, 64);
    if (lane < 16) cw1[w16 + lm] = cws;
    __syncthreads();   // stage(G1,0) drained; cw1/qw2e visible

    float qe[8];
    #pragma unroll
    for (int f = 0; f < 8; ++f) qe[f] = qw2e[f * 16 + lm];
    float cwr[4];
    #pragma unroll
    for (int r = 0; r < 4; ++r) cwr[r] = cw1[w16 + lg * 4 + r];

    const f32x4 vzero = {0.f, 0.f, 0.f, 0.f};
    f32x4 acc[8];
    #pragma unroll
    for (int f = 0; f < 8; ++f) acc[f] = vzero;

    // ---- GEMM1: S[c][q]; B dbuf = SB / PHi-head (P not yet written)
    #pragma unroll
    for (int t = 0; t < 4; ++t) {
        if (t < 3) stage_b(qw3Hb, (t + 1) * 32, ((t + 1) & 1) ? PHi : SB, wv, lane);
        const short* sb = (t & 1) ? PHi : SB;
        bf16x8 aH = aHr[t], aL = aLr[t];
        #pragma unroll
        for (int f = 0; f < 8; ++f) {
            bf16x8 bH = *(const bf16x8*)(sb + (f * 16 + lm) * 32 + lk);
            acc[f] = __builtin_amdgcn_mfma_f32_16x16x32_bf16(aH, bH, acc[f], 0, 0, 0);
            acc[f] = __builtin_amdgcn_mfma_f32_16x16x32_bf16(aL, bH, acc[f], 0, 0, 0);
        }
        __syncthreads();   // drains stage; guards dbuf reuse (and P overlay at t=3)
    }

    // early A-fragments for GEMM2: qT rows d = ds*64 + w16 + lm (reg-resident;
    // issued now so HBM/L2 latency hides under softmax + P-write + barrier)
    bf16x8 qa[2][4];
    #pragma unroll
    for (int ds = 0; ds < 2; ++ds)
        #pragma unroll
        for (int t = 0; t < 4; ++t)
            qa[ds][t] = *(const bf16x8*)(qTHb + (size_t)(ds * 64 + w16 + lm) * 128 + t * 32 + lk);

    // ---- softmax over q; P -> PHi bf16 rne; m,1/s -> LDS
    #pragma unroll
    for (int r = 0; r < 4; ++r) {
        float sv[8];
        float mx = -3.0e38f;
        #pragma unroll
        for (int f = 0; f < 8; ++f) {
            sv[f] = acc[f][r] + qe[f];
            mx = fmaxf(mx, sv[f]);
        }
        mx = fmaxf(mx, __shfl_xor(mx, 1, 16));
        mx = fmaxf(mx, __shfl_xor(mx, 2, 16));
        mx = fmaxf(mx, __shfl_xor(mx, 4, 16));
        mx = fmaxf(mx, __shfl_xor(mx, 8, 16));
        int lrow = w16 + lg * 4 + r;
        float s = 0.f;
        #pragma unroll
        for (int f = 0; f < 8; ++f) {
            float p = __expf(sv[f] - mx);
            s += p;
            PHi[lrow * 136 + f * 16 + lm] = bf16_rne(p);
        }
        s += __shfl_xor(s, 1, 16);
        s += __shfl_xor(s, 2, 16);
        s += __shfl_xor(s, 4, 16);
        s += __shfl_xor(s, 8, 16);
        if (lm == 0) { mlds[lrow] = mx + cwr[r]; slds[lrow] = 1.0f / s; }
    }
    __syncthreads();   // P visible to all waves (cross-wave B reads in G2)

    // ---- GEMM2 (transposed): c2qT[d][c] = sum_q qT[d][q] * P[c][q]
    //      A = qa (regs), B = P (LDS). No staging, no barriers.
    f32x4 acc2[2][4];  // [dset][fc]
    #pragma unroll
    for (int ds = 0; ds < 2; ++ds)
        #pragma unroll
        for (int fc = 0; fc < 4; ++fc) acc2[ds][fc] = vzero;

    #pragma unroll
    for (int t = 0; t < 4; ++t) {
        #pragma unroll
        for (int fc = 0; fc < 4; ++fc) {
            bf16x8 bP = *(const bf16x8*)(PHi + (fc * 16 + lm) * 136 + t * 32 + lk);
            acc2[0][fc] = __builtin_amdgcn_mfma_f32_16x16x32_bf16(qa[0][t], bP, acc2[0][fc], 0, 0, 0);
            acc2[1][fc] = __builtin_amdgcn_mfma_f32_16x16x32_bf16(qa[1][t], bP, acc2[1][fc], 0, 0, 0);
        }
    }
    __syncthreads();   // all PHi reads done before Tr overlay

    // ---- epilogue: 2 passes of 32 c-rows; Tr[c_local][d] overlay; fused q2c
    const int rsel = tid >> 5;            // 0..7
    const int dd   = (tid & 31) * 4;      // 0..124
    float4 qacc = {0.f, 0.f, 0.f, 0.f};
    float denp = 0.f;
    #pragma unroll
    for (int p = 0; p < 2; ++p) {
        // transpose write: lane owns c = fc*16+lm, d = ds*64+w16+lg*4+r (r contiguous)
        #pragma unroll
        for (int fq = 0; fq < 2; ++fq) {
            int fc = 2 * p + fq;
            float ic = slds[fc * 16 + lm];
            int cl = fq * 16 + lm;
            #pragma unroll
            for (int ds = 0; ds < 2; ++ds) {
                f32x4 v = acc2[ds][fc];
                float4 o;
                o.x = v[0] * ic; o.y = v[1] * ic; o.z = v[2] * ic; o.w = v[3] * ic;
                *(float4*)(Tr + cl * 132 + ds * 64 + w16 + lg * 4) = o;
            }
        }
        __syncthreads();
        #pragma unroll
        for (int i = 0; i < 4; ++i) {
            int cl  = i * 8 + rsel;        // 0..31
            int row = p * 32 + cl;
            float4 a  = *(const float4*)(Tr + cl * 132 + dd);
            float4 cv = *(const float4*)(ctxb + (size_t)row * D_ + dd);
            float wgt = __expf(mlds[row] - OFF_);
            size_t obase = ((size_t)b * C_ + c0 + row) * (4 * D_);
            float4 pr;
            pr.x = cv.x*a.x; pr.y = cv.y*a.y; pr.z = cv.z*a.z; pr.w = cv.w*a.w;
            *(float4*)(out + obase + dd)          = cv;
            *(float4*)(out + obase + D_ + dd)     = a;
            *(float4*)(out + obase + 2 * D_ + dd) = pr;
            qacc.x += wgt * cv.x; qacc.y += wgt * cv.y;
            qacc.z += wgt * cv.z; qacc.w += wgt * cv.w;
            denp += wgt;
        }
        __syncthreads();   // Tr reads done before next pass overwrites
    }

    // ---- block q2c partial reduce (red overlays Tr region)
    *(float4*)(red + rsel * 128 + dd) = qacc;
    if ((tid & 31) == 0) dred[rsel] = denp;
    __syncthreads();
    if (tid < 128) {
        float s = 0.f;
        #pragma unroll
        for (int rr = 0; rr < 8; ++rr) s += red[rr * 128 + tid];
        part[((size_t)b * 32 + blockIdx.x) * 128 + tid] = s;
    }
    if (tid == 0) {
        float s = 0.f;
        #pragma unroll
        for (int rr = 0; rr < 8; ++rr) s += dred[rr];
        denp_g[b * 32 + blockIdx.x] = s;
    }
}

// ---------------- q2c: per-batch reduce of 32 partials ----------------
__global__ __launch_bounds__(128)
void cqa_q2c(const float* __restrict__ part, const float* __restrict__ denp_g,
             float* __restrict__ q2c)
{
    int b = blockIdx.x, d = threadIdx.x;
    float den = 0.f;
    #pragma unroll
    for (int j = 0; j < 32; ++j) den += denp_g[b * 32 + j];
    float s = 0.f;
    #pragma unroll
    for (int j = 0; j < 32; ++j) s += part[((size_t)b * 32 + j) * 128 + d];
    q2c[b * 128 + d] = s / den;
}

// ---------------- out[:,:,384:512) = ctx * q2c (broadcast) ----------------
__global__ __launch_bounds__(256)
void cqa_out4(const float* __restrict__ ctx, const float* __restrict__ q2c,
              float* __restrict__ out)
{
    size_t i = (size_t)blockIdx.x * 256 + threadIdx.x;
    const size_t n4 = (size_t)B_*C_*D_/4;
    if (i >= n4) return;
    size_t bc = i >> 5;
    int d4 = (int)(i & 31);
    int b  = (int)(bc >> 11);
    float4 c4 = reinterpret_cast<const float4*>(ctx)[i];
    float4 g4 = reinterpret_cast<const float4*>(q2c)[b*32 + d4];
    float4 o;
    o.x = c4.x*g4.x; o.y = c4.y*g4.y; o.z = c4.z*g4.z; o.w = c4.w*g4.w;
    reinterpret_cast<float4*>(out)[bc*128 + 96 + d4] = o;
}

extern "C" void kernel_launch(void* const* d_in, const int* in_sizes, int n_in,
                              void* d_out, int out_size, void* d_ws, size_t ws_size,
                              hipStream_t stream)
{
    const float* ctx   = (const float*)d_in[0];
    const float* qry   = (const float*)d_in[1];
    const float* w     = (const float*)d_in[2];
    const int*   qmask = (const int*)d_in[3];
    float* out = (float*)d_out;
    float* ws  = (float*)d_ws;

    float* part    = ws;                        // B*32*128 = 131072 f32
    float* denp_g  = ws + 131072;               // 1024
    float* q2c     = ws + 132096;               // 4096
    float* qw2e_g  = ws + 136192;               // 4096
    unsigned short* bf = (unsigned short*)(ws + 140288);
    unsigned short* qw3Hi = bf;                 // 524288 shorts
    unsigned short* qTHi  = bf + 524288;        // 524288 shorts

    cqa_prep<<<dim3(8, B_), 256, 0, stream>>>(qry, w, qmask, qw2e_g, qw3Hi, qTHi);
    cqa_main<<<dim3(C_/CT, B_), 256, 0, stream>>>(ctx, w, qw2e_g, qw3Hi, qTHi,
                                                  out, part, denp_g);
    cqa_q2c<<<B_, 128, 0, stream>>>(part, denp_g, q2c);
    cqa_out4<<<(int)(((size_t)B_*C_*D_/4 + 255)/256), 256, 0, stream>>>(ctx, q2c, out);
}

// Round 14
// 54.152 us; speedup vs baseline: 1.3138x; 1.3138x over previous
//
#include <hip/hip_runtime.h>
#include <cstdint>

#define B_ 32
#define C_ 2048
#define Q_ 128
#define D_ 128
#define CT 64
#define OFF_ 8.0f
#define NEG_INF_F (-1.0e9f)

typedef __attribute__((ext_vector_type(8))) short bf16x8;
typedef __attribute__((ext_vector_type(4))) float f32x4;

__device__ inline short bf16_rne(float v) {
    unsigned u = __float_as_uint(v);
    return (short)((u + 0x7FFFu + ((u >> 16) & 1u)) >> 16);
}
__device__ inline void split_f32(float v, short& h, short& l) {
    unsigned u  = __float_as_uint(v);
    unsigned hb = u & 0xffff0000u;          // truncated bf16 (hi)
    float lo = v - __uint_as_float(hb);     // exact residual
    h = (short)(hb >> 16);
    l = (short)(__float_as_uint(lo) >> 16);
}

// ---------- prep: qw2e (q.w2 + mask), rne-bf16 of (qry*w3) and qry^T ----------
__global__ __launch_bounds__(256)
void cqa_prep(const float* __restrict__ qry, const float* __restrict__ w,
              const int* __restrict__ qmask, float* __restrict__ qw2e_g,
              unsigned short* __restrict__ qw3Hi, unsigned short* __restrict__ qTHi)
{
    const int b = blockIdx.y, ch = blockIdx.x;   // ch: 16-row chunk of q
    const int t = threadIdx.x;
    const float* qb = qry + (size_t)b * Q_ * D_;

    if (t < 32) {
        int rl = t >> 1, part = t & 1;
        int q = ch * 16 + rl;
        const float* p  = qb + q * D_ + part * 64;
        const float* wp = w + D_ + part * 64;
        float s = 0.f;
        #pragma unroll
        for (int j = 0; j < 64; j += 4) {
            float4 a4 = *(const float4*)(p + j);
            float4 w4 = *(const float4*)(wp + j);
            s += a4.x*w4.x + a4.y*w4.y + a4.z*w4.z + a4.w*w4.w;
        }
        s += __shfl_xor(s, 1, 2);
        if (!part) {
            float madd = (1.0f - (float)qmask[b * Q_ + q]) * NEG_INF_F;
            qw2e_g[b * Q_ + q] = s + madd;
        }
    }
    #pragma unroll
    for (int i = 0; i < 8; ++i) {
        int idx = t + i * 256;            // 16 rows x 128 d
        int ql = idx >> 7, d = idx & 127;
        int q = ch * 16 + ql;
        float v = qb[q * D_ + d];
        qw3Hi[((size_t)b * Q_ + q) * D_ + d] = (unsigned short)bf16_rne(v * w[2 * D_ + d]);
        qTHi[((size_t)b * D_ + d) * Q_ + q]  = (unsigned short)bf16_rne(v);
    }
}

// stage cols [col0,col0+32) of a [128][128]-short row-major matrix into an
// 8KB LDS buffer [128][32] via async DMA (linear LDS dest = base + lane*16B).
__device__ __forceinline__ void stage_b(const unsigned short* __restrict__ gH,
                                        int col0, short* sb, int wv, int lane)
{
    #pragma unroll
    for (int j = 0; j < 2; ++j) {
        int seg = wv * 2 + j;                 // 1KB segment 0..7
        int li  = seg * 64 + lane;            // 16B-unit linear index 0..511
        int row = li >> 2;
        int col = (li & 3) * 8;
        __builtin_amdgcn_global_load_lds(
            (const __attribute__((address_space(1))) void*)(gH + (size_t)row * 128 + col0 + col),
            (__attribute__((address_space(3))) void*)(sb + seg * 512), 16, 0, 0);
    }
}

// ---------- main: G1 (dbuf DMA) + softmax + G2 (reg-A x P-LDS, no staging) ----------
// launch_bounds(256,5): VGPR cap 102 (peak live ~90, no spill); LDS 27KB -> 5 blk/CU.
// (256,6) capped VGPR at 85 -> scratch spills -> R13's 71us regression.
__global__ __launch_bounds__(256, 5)
void cqa_main(const float* __restrict__ ctx, const float* __restrict__ w,
              const float* __restrict__ qw2e_g,
              const unsigned short* __restrict__ qw3Hi, const unsigned short* __restrict__ qTHi,
              float* __restrict__ out, float* __restrict__ part, float* __restrict__ denp_g)
{
    __shared__ __align__(16) char smem[27008];
    short* SB   = (short*)smem;                 // [0,8192): G1 stage buf 0
    short* PHi  = (short*)(smem + 8192);        // [64][136] bf16; first 8KB = G1 buf 1
    float* Tr   = (float*)smem;                 // [32][132] f32 epilogue overlay (16896 B)
    float* red  = (float*)smem;                 // [8][128] f32 overlay (post-Tr)
    float* mlds = (float*)(smem + 25600);       // 64 f32
    float* slds = (float*)(smem + 25856);       // 64 f32 (1/rowsum)
    float* cw1  = (float*)(smem + 26112);       // 64 f32
    float* qw2e = (float*)(smem + 26368);       // 128 f32
    float* dred = (float*)(smem + 26880);       // 8 f32

    const int b   = blockIdx.y;
    const int c0  = blockIdx.x * CT;
    const int tid = threadIdx.x;
    const int lane = tid & 63;
    const int wv   = tid >> 6;
    const int w16  = wv * 16;
    const int lm   = lane & 15;
    const int lg   = lane >> 4;    // 0..3
    const int lk   = lg * 8;       // k-slot start within 32-chunk

    const float* ctxb = ctx + ((size_t)b * C_ + c0) * D_;
    const unsigned short* qw3Hb = qw3Hi + (size_t)b * Q_ * D_;
    const unsigned short* qTHb  = qTHi + (size_t)b * Q_ * D_;

    // kick off DMA of GEMM1 chunk 0 immediately (buf0)
    stage_b(qw3Hb, 0, SB, wv, lane);

    if (tid < Q_) qw2e[tid] = qw2e_g[b * Q_ + tid];

    // A-preload (ctx rows, exact hi/lo split) with fused cw1 = ctx_row . w1
    const float* arow = ctxb + (size_t)(w16 + lm) * D_;
    bf16x8 aHr[4], aLr[4];
    float cws = 0.f;
    #pragma unroll
    for (int t = 0; t < 4; ++t) {
        float4 v0 = *(const float4*)(arow + t * 32 + lk);
        float4 v1 = *(const float4*)(arow + t * 32 + lk + 4);
        float4 w0 = *(const float4*)(w + t * 32 + lk);
        float4 w1v = *(const float4*)(w + t * 32 + lk + 4);
        cws += v0.x*w0.x + v0.y*w0.y + v0.z*w0.z + v0.w*w0.w
             + v1.x*w1v.x + v1.y*w1v.y + v1.z*w1v.z + v1.w*w1v.w;
        float vv[8] = {v0.x, v0.y, v0.z, v0.w, v1.x, v1.y, v1.z, v1.w};
        #pragma unroll
        for (int i = 0; i < 8; ++i) {
            short hh, ll; split_f32(vv[i], hh, ll);
            aHr[t][i] = hh; aLr[t][i] = ll;
        }
    }
    cws += __shfl_xor(cws, 16, 64);
    cws += __shfl_xor(cws, 32, 64);
    if (lane < 16) cw1[w16 + lm] = cws;
    __syncthreads();   // stage(G1,0) drained; cw1/qw2e visible

    float qe[8];
    #pragma unroll
    for (int f = 0; f < 8; ++f) qe[f] = qw2e[f * 16 + lm];
    float cwr[4];
    #pragma unroll
    for (int r = 0; r < 4; ++r) cwr[r] = cw1[w16 + lg * 4 + r];

    const f32x4 vzero = {0.f, 0.f, 0.f, 0.f};
    f32x4 acc[8];
    #pragma unroll
    for (int f = 0; f < 8; ++f) acc[f] = vzero;

    // ---- GEMM1: S[c][q]; B dbuf = SB / PHi-head (P not yet written)
    #pragma unroll
    for (int t = 0; t < 4; ++t) {
        if (t < 3) stage_b(qw3Hb, (t + 1) * 32, ((t + 1) & 1) ? PHi : SB, wv, lane);
        const short* sb = (t & 1) ? PHi : SB;
        bf16x8 aH = aHr[t], aL = aLr[t];
        #pragma unroll
        for (int f = 0; f < 8; ++f) {
            bf16x8 bH = *(const bf16x8*)(sb + (f * 16 + lm) * 32 + lk);
            acc[f] = __builtin_amdgcn_mfma_f32_16x16x32_bf16(aH, bH, acc[f], 0, 0, 0);
            acc[f] = __builtin_amdgcn_mfma_f32_16x16x32_bf16(aL, bH, acc[f], 0, 0, 0);
        }
        __syncthreads();   // drains stage; guards dbuf reuse (and P overlay at t=3)
    }

    // early A-fragments for GEMM2: qT rows d = ds*64 + w16 + lm (reg-resident;
    // issued now so HBM/L2 latency hides under softmax + P-write + barrier)
    bf16x8 qa[2][4];
    #pragma unroll
    for (int ds = 0; ds < 2; ++ds)
        #pragma unroll
        for (int t = 0; t < 4; ++t)
            qa[ds][t] = *(const bf16x8*)(qTHb + (size_t)(ds * 64 + w16 + lm) * 128 + t * 32 + lk);

    // ---- softmax over q; P -> PHi bf16 rne; m,1/s -> LDS
    #pragma unroll
    for (int r = 0; r < 4; ++r) {
        float sv[8];
        float mx = -3.0e38f;
        #pragma unroll
        for (int f = 0; f < 8; ++f) {
            sv[f] = acc[f][r] + qe[f];
            mx = fmaxf(mx, sv[f]);
        }
        mx = fmaxf(mx, __shfl_xor(mx, 1, 16));
        mx = fmaxf(mx, __shfl_xor(mx, 2, 16));
        mx = fmaxf(mx, __shfl_xor(mx, 4, 16));
        mx = fmaxf(mx, __shfl_xor(mx, 8, 16));
        int lrow = w16 + lg * 4 + r;
        float s = 0.f;
        #pragma unroll
        for (int f = 0; f < 8; ++f) {
            float p = __expf(sv[f] - mx);
            s += p;
            PHi[lrow * 136 + f * 16 + lm] = bf16_rne(p);
        }
        s += __shfl_xor(s, 1, 16);
        s += __shfl_xor(s, 2, 16);
        s += __shfl_xor(s, 4, 16);
        s += __shfl_xor(s, 8, 16);
        if (lm == 0) { mlds[lrow] = mx + cwr[r]; slds[lrow] = 1.0f / s; }
    }
    __syncthreads();   // P visible to all waves (cross-wave B reads in G2)

    // ---- GEMM2 (transposed): c2qT[d][c] = sum_q qT[d][q] * P[c][q]
    //      A = qa (regs), B = P (LDS). No staging, no barriers.
    f32x4 acc2[2][4];  // [dset][fc]
    #pragma unroll
    for (int ds = 0; ds < 2; ++ds)
        #pragma unroll
        for (int fc = 0; fc < 4; ++fc) acc2[ds][fc] = vzero;

    #pragma unroll
    for (int t = 0; t < 4; ++t) {
        #pragma unroll
        for (int fc = 0; fc < 4; ++fc) {
            bf16x8 bP = *(const bf16x8*)(PHi + (fc * 16 + lm) * 136 + t * 32 + lk);
            acc2[0][fc] = __builtin_amdgcn_mfma_f32_16x16x32_bf16(qa[0][t], bP, acc2[0][fc], 0, 0, 0);
            acc2[1][fc] = __builtin_amdgcn_mfma_f32_16x16x32_bf16(qa[1][t], bP, acc2[1][fc], 0, 0, 0);
        }
    }
    __syncthreads();   // all PHi reads done before Tr overlay

    // ---- epilogue: 2 passes of 32 c-rows; Tr[c_local][d] overlay; fused q2c
    const int rsel = tid >> 5;            // 0..7
    const int dd   = (tid & 31) * 4;      // 0..124
    float4 qacc = {0.f, 0.f, 0.f, 0.f};
    float denp = 0.f;
    #pragma unroll
    for (int p = 0; p < 2; ++p) {
        // transpose write: lane owns c = fc*16+lm, d = ds*64+w16+lg*4+r (r contiguous)
        #pragma unroll
        for (int fq = 0; fq < 2; ++fq) {
            int fc = 2 * p + fq;
            float ic = slds[fc * 16 + lm];
            int cl = fq * 16 + lm;
            #pragma unroll
            for (int ds = 0; ds < 2; ++ds) {
                f32x4 v = acc2[ds][fc];
                float4 o;
                o.x = v[0] * ic; o.y = v[1] * ic; o.z = v[2] * ic; o.w = v[3] * ic;
                *(float4*)(Tr + cl * 132 + ds * 64 + w16 + lg * 4) = o;
            }
        }
        __syncthreads();
        #pragma unroll
        for (int i = 0; i < 4; ++i) {
            int cl  = i * 8 + rsel;        // 0..31
            int row = p * 32 + cl;
            float4 a  = *(const float4*)(Tr + cl * 132 + dd);
            float4 cv = *(const float4*)(ctxb + (size_t)row * D_ + dd);
            float wgt = __expf(mlds[row] - OFF_);
            size_t obase = ((size_t)b * C_ + c0 + row) * (4 * D_);
            float4 pr;
            pr.x = cv.x*a.x; pr.y = cv.y*a.y; pr.z = cv.z*a.z; pr.w = cv.w*a.w;
            *(float4*)(out + obase + dd)          = cv;
            *(float4*)(out + obase + D_ + dd)     = a;
            *(float4*)(out + obase + 2 * D_ + dd) = pr;
            qacc.x += wgt * cv.x; qacc.y += wgt * cv.y;
            qacc.z += wgt * cv.z; qacc.w += wgt * cv.w;
            denp += wgt;
        }
        __syncthreads();   // Tr reads done before next pass overwrites
    }

    // ---- block q2c partial reduce (red overlays Tr region)
    *(float4*)(red + rsel * 128 + dd) = qacc;
    if ((tid & 31) == 0) dred[rsel] = denp;
    __syncthreads();
    if (tid < 128) {
        float s = 0.f;
        #pragma unroll
        for (int rr = 0; rr < 8; ++rr) s += red[rr * 128 + tid];
        part[((size_t)b * 32 + blockIdx.x) * 128 + tid] = s;
    }
    if (tid == 0) {
        float s = 0.f;
        #pragma unroll
        for (int rr = 0; rr < 8; ++rr) s += dred[rr];
        denp_g[b * 32 + blockIdx.x] = s;
    }
}

// ---------------- q2c: per-batch reduce of 32 partials ----------------
__global__ __launch_bounds__(128)
void cqa_q2c(const float* __restrict__ part, const float* __restrict__ denp_g,
             float* __restrict__ q2c)
{
    int b = blockIdx.x, d = threadIdx.x;
    float den = 0.f;
    #pragma unroll
    for (int j = 0; j < 32; ++j) den += denp_g[b * 32 + j];
    float s = 0.f;
    #pragma unroll
    for (int j = 0; j < 32; ++j) s += part[((size_t)b * 32 + j) * 128 + d];
    q2c[b * 128 + d] = s / den;
}

// ---------------- out[:,:,384:512) = ctx * q2c (broadcast) ----------------
__global__ __launch_bounds__(256)
void cqa_out4(const float* __restrict__ ctx, const float* __restrict__ q2c,
              float* __restrict__ out)
{
    size_t i = (size_t)blockIdx.x * 256 + threadIdx.x;
    const size_t n4 = (size_t)B_*C_*D_/4;
    if (i >= n4) return;
    size_t bc = i >> 5;
    int d4 = (int)(i & 31);
    int b  = (int)(bc >> 11);
    float4 c4 = reinterpret_cast<const float4*>(ctx)[i];
    float4 g4 = reinterpret_cast<const float4*>(q2c)[b*32 + d4];
    float4 o;
    o.x = c4.x*g4.x; o.y = c4.y*g4.y; o.z = c4.z*g4.z; o.w = c4.w*g4.w;
    reinterpret_cast<float4*>(out)[bc*128 + 96 + d4] = o;
}

extern "C" void kernel_launch(void* const* d_in, const int* in_sizes, int n_in,
                              void* d_out, int out_size, void* d_ws, size_t ws_size,
                              hipStream_t stream)
{
    const float* ctx   = (const float*)d_in[0];
    const float* qry   = (const float*)d_in[1];
    const float* w     = (const float*)d_in[2];
    const int*   qmask = (const int*)d_in[3];
    float* out = (float*)d_out;
    float* ws  = (float*)d_ws;

    float* part    = ws;                        // B*32*128 = 131072 f32
    float* denp_g  = ws + 131072;               // 1024
    float* q2c     = ws + 132096;               // 4096
    float* qw2e_g  = ws + 136192;               // 4096
    unsigned short* bf = (unsigned short*)(ws + 140288);
    unsigned short* qw3Hi = bf;                 // 524288 shorts
    unsigned short* qTHi  = bf + 524288;        // 524288 shorts

    cqa_prep<<<dim3(8, B_), 256, 0, stream>>>(qry, w, qmask, qw2e_g, qw3Hi, qTHi);
    cqa_main<<<dim3(C_/CT, B_), 256, 0, stream>>>(ctx, w, qw2e_g, qw3Hi, qTHi,
                                                  out, part, denp_g);
    cqa_q2c<<<B_, 128, 0, stream>>>(part, denp_g, q2c);
    cqa_out4<<<(int)(((size_t)B_*C_*D_/4 + 255)/256), 256, 0, stream>>>(ctx, q2c, out);
}

// Round 15
// 52.750 us; speedup vs baseline: 1.3487x; 1.0266x over previous
//
#include <hip/hip_runtime.h>
#include <cstdint>

#define B_ 32
#define C_ 2048
#define Q_ 128
#define D_ 128
#define CT 64
#define OFF_ 8.0f
#define NEG_INF_F (-1.0e9f)

typedef __attribute__((ext_vector_type(8))) short bf16x8;
typedef __attribute__((ext_vector_type(4))) float f32x4;

__device__ inline short bf16_rne(float v) {
    unsigned u = __float_as_uint(v);
    return (short)((u + 0x7FFFu + ((u >> 16) & 1u)) >> 16);
}
__device__ inline void split_f32(float v, short& h, short& l) {
    unsigned u  = __float_as_uint(v);
    unsigned hb = u & 0xffff0000u;          // truncated bf16 (hi)
    float lo = v - __uint_as_float(hb);     // exact residual
    h = (short)(hb >> 16);
    l = (short)(__float_as_uint(lo) >> 16);
}

// ---------- prep: qw2e (q.w2 + mask), rne-bf16 of (qry*w3) and qry^T ----------
__global__ __launch_bounds__(256)
void cqa_prep(const float* __restrict__ qry, const float* __restrict__ w,
              const int* __restrict__ qmask, float* __restrict__ qw2e_g,
              unsigned short* __restrict__ qw3Hi, unsigned short* __restrict__ qTHi)
{
    const int b = blockIdx.y, ch = blockIdx.x;   // ch: 16-row chunk of q
    const int t = threadIdx.x;
    const float* qb = qry + (size_t)b * Q_ * D_;

    if (t < 32) {
        int rl = t >> 1, part = t & 1;
        int q = ch * 16 + rl;
        const float* p  = qb + q * D_ + part * 64;
        const float* wp = w + D_ + part * 64;
        float s = 0.f;
        #pragma unroll
        for (int j = 0; j < 64; j += 4) {
            float4 a4 = *(const float4*)(p + j);
            float4 w4 = *(const float4*)(wp + j);
            s += a4.x*w4.x + a4.y*w4.y + a4.z*w4.z + a4.w*w4.w;
        }
        s += __shfl_xor(s, 1, 2);
        if (!part) {
            float madd = (1.0f - (float)qmask[b * Q_ + q]) * NEG_INF_F;
            qw2e_g[b * Q_ + q] = s + madd;
        }
    }
    #pragma unroll
    for (int i = 0; i < 8; ++i) {
        int idx = t + i * 256;            // 16 rows x 128 d
        int ql = idx >> 7, d = idx & 127;
        int q = ch * 16 + ql;
        float v = qb[q * D_ + d];
        qw3Hi[((size_t)b * Q_ + q) * D_ + d] = (unsigned short)bf16_rne(v * w[2 * D_ + d]);
        qTHi[((size_t)b * D_ + d) * Q_ + q]  = (unsigned short)bf16_rne(v);
    }
}

// stage cols [col0,col0+32) of a [128][128]-short row-major matrix into an
// 8KB LDS buffer [128][32] via async DMA (linear LDS dest = base + lane*16B).
__device__ __forceinline__ void stage_b(const unsigned short* __restrict__ gH,
                                        int col0, short* sb, int wv, int lane)
{
    #pragma unroll
    for (int j = 0; j < 2; ++j) {
        int seg = wv * 2 + j;                 // 1KB segment 0..7
        int li  = seg * 64 + lane;            // 16B-unit linear index 0..511
        int row = li >> 2;
        int col = (li & 3) * 8;
        __builtin_amdgcn_global_load_lds(
            (const __attribute__((address_space(1))) void*)(gH + (size_t)row * 128 + col0 + col),
            (__attribute__((address_space(3))) void*)(sb + seg * 512), 16, 0, 0);
    }
}

// ---------- main: one-shot-staged G1 + softmax + reg-A G2 + fused q2c ----------
// All 4 qw3 chunks DMA'd at start; ONE drain barrier (hidden under A-preload).
// G1 runs 64 MFMA with no internal barriers (was 4 DMA->barrier round-trips).
__global__ __launch_bounds__(256, 4)
void cqa_main(const float* __restrict__ ctx, const float* __restrict__ w,
              const float* __restrict__ qw2e_g,
              const unsigned short* __restrict__ qw3Hi, const unsigned short* __restrict__ qTHi,
              float* __restrict__ out, float* __restrict__ part, float* __restrict__ denp_g)
{
    __shared__ __align__(16) char smem[34176];
    short* SB   = (short*)smem;                 // [0,32768): 4 x [128][32] one-shot stage
    short* PHi  = (short*)smem;                 // [64][136] bf16 overlay post-G1 (17408 B)
    float* Tr   = (float*)smem;                 // [32][132] f32 overlay post-G2 (16896 B)
    float* red  = (float*)smem;                 // [8][128] f32 overlay post-Tr
    float* mlds = (float*)(smem + 32768);       // 64 f32
    float* slds = (float*)(smem + 33024);       // 64 f32 (1/rowsum)
    float* cw1  = (float*)(smem + 33280);       // 64 f32
    float* qw2e = (float*)(smem + 33536);       // 128 f32
    float* dred = (float*)(smem + 34048);       // 8 f32

    const int b   = blockIdx.y;
    const int c0  = blockIdx.x * CT;
    const int tid = threadIdx.x;
    const int lane = tid & 63;
    const int wv   = tid >> 6;
    const int w16  = wv * 16;
    const int lm   = lane & 15;
    const int lg   = lane >> 4;    // 0..3
    const int lk   = lg * 8;       // k-slot start within 32-chunk

    const float* ctxb = ctx + ((size_t)b * C_ + c0) * D_;
    const unsigned short* qw3Hb = qw3Hi + (size_t)b * Q_ * D_;
    const unsigned short* qTHb  = qTHi + (size_t)b * Q_ * D_;

    // one-shot: DMA ALL FOUR qw3 chunks now (8 global_load_lds per wave)
    #pragma unroll
    for (int t = 0; t < 4; ++t)
        stage_b(qw3Hb, t * 32, SB + t * 4096, wv, lane);

    if (tid < Q_) qw2e[tid] = qw2e_g[b * Q_ + tid];

    // A-preload (ctx rows, exact hi/lo split) with fused cw1 = ctx_row . w1;
    // this work hides the staging DMA latency before the single drain barrier
    const float* arow = ctxb + (size_t)(w16 + lm) * D_;
    bf16x8 aHr[4], aLr[4];
    float cws = 0.f;
    #pragma unroll
    for (int t = 0; t < 4; ++t) {
        float4 v0 = *(const float4*)(arow + t * 32 + lk);
        float4 v1 = *(const float4*)(arow + t * 32 + lk + 4);
        float4 w0 = *(const float4*)(w + t * 32 + lk);
        float4 w1v = *(const float4*)(w + t * 32 + lk + 4);
        cws += v0.x*w0.x + v0.y*w0.y + v0.z*w0.z + v0.w*w0.w
             + v1.x*w1v.x + v1.y*w1v.y + v1.z*w1v.z + v1.w*w1v.w;
        float vv[8] = {v0.x, v0.y, v0.z, v0.w, v1.x, v1.y, v1.z, v1.w};
        #pragma unroll
        for (int i = 0; i < 8; ++i) {
            short hh, ll; split_f32(vv[i], hh, ll);
            aHr[t][i] = hh; aLr[t][i] = ll;
        }
    }
    cws += __shfl_xor(cws, 16, 64);
    cws += __shfl_xor(cws, 32, 64);
    if (lane < 16) cw1[w16 + lm] = cws;
    __syncthreads();   // single drain: all 4 stage chunks + cw1/qw2e visible

    float qe[8];
    #pragma unroll
    for (int f = 0; f < 8; ++f) qe[f] = qw2e[f * 16 + lm];
    float cwr[4];
    #pragma unroll
    for (int r = 0; r < 4; ++r) cwr[r] = cw1[w16 + lg * 4 + r];

    const f32x4 vzero = {0.f, 0.f, 0.f, 0.f};
    f32x4 acc[8];
    #pragma unroll
    for (int f = 0; f < 8; ++f) acc[f] = vzero;

    // ---- GEMM1: S[c][q]; 64 MFMA, zero barriers
    #pragma unroll
    for (int t = 0; t < 4; ++t) {
        const short* sb = SB + t * 4096;
        bf16x8 aH = aHr[t], aL = aLr[t];
        #pragma unroll
        for (int f = 0; f < 8; ++f) {
            bf16x8 bH = *(const bf16x8*)(sb + (f * 16 + lm) * 32 + lk);
            acc[f] = __builtin_amdgcn_mfma_f32_16x16x32_bf16(aH, bH, acc[f], 0, 0, 0);
            acc[f] = __builtin_amdgcn_mfma_f32_16x16x32_bf16(aL, bH, acc[f], 0, 0, 0);
        }
    }
    __syncthreads();   // all stage reads done before PHi overlay

    // GEMM2 A-fragments: qT rows d = ds*64 + w16 + lm; latency hides under softmax
    bf16x8 qa[2][4];
    #pragma unroll
    for (int ds = 0; ds < 2; ++ds)
        #pragma unroll
        for (int t = 0; t < 4; ++t)
            qa[ds][t] = *(const bf16x8*)(qTHb + (size_t)(ds * 64 + w16 + lm) * 128 + t * 32 + lk);

    // ---- softmax over q; P -> PHi bf16 rne; m,1/s -> LDS
    #pragma unroll
    for (int r = 0; r < 4; ++r) {
        float sv[8];
        float mx = -3.0e38f;
        #pragma unroll
        for (int f = 0; f < 8; ++f) {
            sv[f] = acc[f][r] + qe[f];
            mx = fmaxf(mx, sv[f]);
        }
        mx = fmaxf(mx, __shfl_xor(mx, 1, 16));
        mx = fmaxf(mx, __shfl_xor(mx, 2, 16));
        mx = fmaxf(mx, __shfl_xor(mx, 4, 16));
        mx = fmaxf(mx, __shfl_xor(mx, 8, 16));
        int lrow = w16 + lg * 4 + r;
        float s = 0.f;
        #pragma unroll
        for (int f = 0; f < 8; ++f) {
            float p = __expf(sv[f] - mx);
            s += p;
            PHi[lrow * 136 + f * 16 + lm] = bf16_rne(p);
        }
        s += __shfl_xor(s, 1, 16);
        s += __shfl_xor(s, 2, 16);
        s += __shfl_xor(s, 4, 16);
        s += __shfl_xor(s, 8, 16);
        if (lm == 0) { mlds[lrow] = mx + cwr[r]; slds[lrow] = 1.0f / s; }
    }
    __syncthreads();   // P visible to all waves (cross-wave B reads in G2)

    // ---- GEMM2 (transposed): c2qT[d][c] = sum_q qT[d][q] * P[c][q]
    f32x4 acc2[2][4];  // [dset][fc]
    #pragma unroll
    for (int ds = 0; ds < 2; ++ds)
        #pragma unroll
        for (int fc = 0; fc < 4; ++fc) acc2[ds][fc] = vzero;

    #pragma unroll
    for (int t = 0; t < 4; ++t) {
        #pragma unroll
        for (int fc = 0; fc < 4; ++fc) {
            bf16x8 bP = *(const bf16x8*)(PHi + (fc * 16 + lm) * 136 + t * 32 + lk);
            acc2[0][fc] = __builtin_amdgcn_mfma_f32_16x16x32_bf16(qa[0][t], bP, acc2[0][fc], 0, 0, 0);
            acc2[1][fc] = __builtin_amdgcn_mfma_f32_16x16x32_bf16(qa[1][t], bP, acc2[1][fc], 0, 0, 0);
        }
    }
    __syncthreads();   // all PHi reads done before Tr overlay

    // ---- epilogue: 2 passes of 32 c-rows; Tr[c_local][d] overlay; fused q2c
    const int rsel = tid >> 5;            // 0..7
    const int dd   = (tid & 31) * 4;      // 0..124
    float4 qacc = {0.f, 0.f, 0.f, 0.f};
    float denp = 0.f;
    #pragma unroll
    for (int p = 0; p < 2; ++p) {
        #pragma unroll
        for (int fq = 0; fq < 2; ++fq) {
            int fc = 2 * p + fq;
            float ic = slds[fc * 16 + lm];
            int cl = fq * 16 + lm;
            #pragma unroll
            for (int ds = 0; ds < 2; ++ds) {
                f32x4 v = acc2[ds][fc];
                float4 o;
                o.x = v[0] * ic; o.y = v[1] * ic; o.z = v[2] * ic; o.w = v[3] * ic;
                *(float4*)(Tr + cl * 132 + ds * 64 + w16 + lg * 4) = o;
            }
        }
        __syncthreads();
        #pragma unroll
        for (int i = 0; i < 4; ++i) {
            int cl  = i * 8 + rsel;        // 0..31
            int row = p * 32 + cl;
            float4 a  = *(const float4*)(Tr + cl * 132 + dd);
            float4 cv = *(const float4*)(ctxb + (size_t)row * D_ + dd);
            float wgt = __expf(mlds[row] - OFF_);
            size_t obase = ((size_t)b * C_ + c0 + row) * (4 * D_);
            float4 pr;
            pr.x = cv.x*a.x; pr.y = cv.y*a.y; pr.z = cv.z*a.z; pr.w = cv.w*a.w;
            *(float4*)(out + obase + dd)          = cv;
            *(float4*)(out + obase + D_ + dd)     = a;
            *(float4*)(out + obase + 2 * D_ + dd) = pr;
            qacc.x += wgt * cv.x; qacc.y += wgt * cv.y;
            qacc.z += wgt * cv.z; qacc.w += wgt * cv.w;
            denp += wgt;
        }
        __syncthreads();   // Tr reads done before next pass overwrites
    }

    // ---- block q2c partial reduce (red overlays Tr region)
    *(float4*)(red + rsel * 128 + dd) = qacc;
    if ((tid & 31) == 0) dred[rsel] = denp;
    __syncthreads();
    if (tid < 128) {
        float s = 0.f;
        #pragma unroll
        for (int rr = 0; rr < 8; ++rr) s += red[rr * 128 + tid];
        part[((size_t)b * 32 + blockIdx.x) * 128 + tid] = s;
    }
    if (tid == 0) {
        float s = 0.f;
        #pragma unroll
        for (int rr = 0; rr < 8; ++rr) s += dred[rr];
        denp_g[b * 32 + blockIdx.x] = s;
    }
}

// ---------------- out4 (+fused q2c reduce): slice 3 = ctx * q2c ----------------
__global__ __launch_bounds__(256)
void cqa_out4(const float* __restrict__ ctx, const float* __restrict__ part,
              const float* __restrict__ denp_g, float* __restrict__ out)
{
    const int b = blockIdx.y, ch = blockIdx.x;   // ch: 64-row chunk
    const int tid = threadIdx.x;
    __shared__ float q2s[128];

    float den = 0.f;
    #pragma unroll 8
    for (int j = 0; j < 32; ++j) den += denp_g[b * 32 + j];
    if (tid < 128) {
        float s = 0.f;
        #pragma unroll 8
        for (int j = 0; j < 32; ++j) s += part[((size_t)b * 32 + j) * 128 + tid];
        q2s[tid] = s / den;
    }
    __syncthreads();

    const float* cb = ctx + ((size_t)b * C_ + ch * 64) * D_;
    float* ob = out + ((size_t)b * C_ + ch * 64) * (4 * D_);
    #pragma unroll
    for (int k = 0; k < 8; ++k) {
        int i  = tid + k * 256;          // 0..2047
        int rl = i >> 5, d4 = (i & 31) * 4;
        float4 c4 = *(const float4*)(cb + (size_t)rl * D_ + d4);
        float4 g4 = *(const float4*)(q2s + d4);
        float4 o;
        o.x = c4.x*g4.x; o.y = c4.y*g4.y; o.z = c4.z*g4.z; o.w = c4.w*g4.w;
        *(float4*)(ob + (size_t)rl * (4 * D_) + 3 * D_ + d4) = o;
    }
}

extern "C" void kernel_launch(void* const* d_in, const int* in_sizes, int n_in,
                              void* d_out, int out_size, void* d_ws, size_t ws_size,
                              hipStream_t stream)
{
    const float* ctx   = (const float*)d_in[0];
    const float* qry   = (const float*)d_in[1];
    const float* w     = (const float*)d_in[2];
    const int*   qmask = (const int*)d_in[3];
    float* out = (float*)d_out;
    float* ws  = (float*)d_ws;

    float* part    = ws;                        // B*32*128 = 131072 f32
    float* denp_g  = ws + 131072;               // 1024
    float* qw2e_g  = ws + 132096;               // 4096
    unsigned short* bf = (unsigned short*)(ws + 136192);
    unsigned short* qw3Hi = bf;                 // 524288 shorts
    unsigned short* qTHi  = bf + 524288;        // 524288 shorts

    cqa_prep<<<dim3(8, B_), 256, 0, stream>>>(qry, w, qmask, qw2e_g, qw3Hi, qTHi);
    cqa_main<<<dim3(C_/CT, B_), 256, 0, stream>>>(ctx, w, qw2e_g, qw3Hi, qTHi,
                                                  out, part, denp_g);
    cqa_out4<<<dim3(C_/64, B_), 256, 0, stream>>>(ctx, part, denp_g, out);
}

// Round 16
// 51.535 us; speedup vs baseline: 1.3805x; 1.0236x over previous
//
#include <hip/hip_runtime.h>
#include <cstdint>

#define B_ 32
#define C_ 2048
#define Q_ 128
#define D_ 128
#define CT 64
#define OFF_ 8.0f
#define NEG_INF_F (-1.0e9f)

typedef __attribute__((ext_vector_type(8))) short bf16x8;
typedef __attribute__((ext_vector_type(4))) float f32x4;

__device__ inline short bf16_rne(float v) {
    unsigned u = __float_as_uint(v);
    return (short)((u + 0x7FFFu + ((u >> 16) & 1u)) >> 16);
}
__device__ inline void split_f32(float v, short& h, short& l) {
    unsigned u  = __float_as_uint(v);
    unsigned hb = u & 0xffff0000u;          // truncated bf16 (hi)
    float lo = v - __uint_as_float(hb);     // exact residual
    h = (short)(hb >> 16);
    l = (short)(__float_as_uint(lo) >> 16);
}

// batch-contiguous XCD swizzle: default dispatch round-robins linear id % 8
// across XCDs; this mapping gives every batch's 32 blocks the SAME id%8, so
// the batch's shared qw3/qT/part lines live in one XCD L2 (bijective, 1024%8==0).
__device__ __forceinline__ void swz(int id, int& b, int& cch) {
    b   = (id & 7) * 4 + (id >> 8);
    cch = (id >> 3) & 31;
}

// ---------- prep: qw2e (q.w2 + mask), rne-bf16 of (qry*w3) and qry^T ----------
__global__ __launch_bounds__(256)
void cqa_prep(const float* __restrict__ qry, const float* __restrict__ w,
              const int* __restrict__ qmask, float* __restrict__ qw2e_g,
              unsigned short* __restrict__ qw3Hi, unsigned short* __restrict__ qTHi)
{
    const int b = blockIdx.y, ch = blockIdx.x;   // ch: 16-row chunk of q
    const int t = threadIdx.x;
    const float* qb = qry + (size_t)b * Q_ * D_;

    if (t < 32) {
        int rl = t >> 1, part = t & 1;
        int q = ch * 16 + rl;
        const float* p  = qb + q * D_ + part * 64;
        const float* wp = w + D_ + part * 64;
        float s = 0.f;
        #pragma unroll
        for (int j = 0; j < 64; j += 4) {
            float4 a4 = *(const float4*)(p + j);
            float4 w4 = *(const float4*)(wp + j);
            s += a4.x*w4.x + a4.y*w4.y + a4.z*w4.z + a4.w*w4.w;
        }
        s += __shfl_xor(s, 1, 2);
        if (!part) {
            float madd = (1.0f - (float)qmask[b * Q_ + q]) * NEG_INF_F;
            qw2e_g[b * Q_ + q] = s + madd;
        }
    }
    #pragma unroll
    for (int i = 0; i < 8; ++i) {
        int idx = t + i * 256;            // 16 rows x 128 d
        int ql = idx >> 7, d = idx & 127;
        int q = ch * 16 + ql;
        float v = qb[q * D_ + d];
        qw3Hi[((size_t)b * Q_ + q) * D_ + d] = (unsigned short)bf16_rne(v * w[2 * D_ + d]);
        qTHi[((size_t)b * D_ + d) * Q_ + q]  = (unsigned short)bf16_rne(v);
    }
}

// stage cols [col0,col0+32) of a [128][128]-short row-major matrix into an
// 8KB LDS buffer [128][32] via async DMA (linear LDS dest = base + lane*16B).
__device__ __forceinline__ void stage_b(const unsigned short* __restrict__ gH,
                                        int col0, short* sb, int wv, int lane)
{
    #pragma unroll
    for (int j = 0; j < 2; ++j) {
        int seg = wv * 2 + j;                 // 1KB segment 0..7
        int li  = seg * 64 + lane;            // 16B-unit linear index 0..511
        int row = li >> 2;
        int col = (li & 3) * 8;
        __builtin_amdgcn_global_load_lds(
            (const __attribute__((address_space(1))) void*)(gH + (size_t)row * 128 + col0 + col),
            (__attribute__((address_space(3))) void*)(sb + seg * 512), 16, 0, 0);
    }
}

// ---------- main: one-shot-staged G1 + softmax + split G2 || epilogue ----------
// Tr no longer aliases PHi, so G2 runs per column-pair interleaved with the
// store passes (pass-1 MFMAs overlap pass-0 store drain).
__global__ __launch_bounds__(256, 4)
void cqa_main(const float* __restrict__ ctx, const float* __restrict__ w,
              const float* __restrict__ qw2e_g,
              const unsigned short* __restrict__ qw3Hi, const unsigned short* __restrict__ qTHi,
              float* __restrict__ out, float* __restrict__ part, float* __restrict__ denp_g)
{
    __shared__ __align__(16) char smem[35648];
    short* SB   = (short*)smem;                 // [0,32768): 4 x [128][32] one-shot stage
    short* PHi  = (short*)smem;                 // [64][136] overlay post-G1 (17408 B)
    float* Tr   = (float*)(smem + 17408);       // [32][132] f32 (ends 34304; != PHi)
    float* red  = (float*)smem;                 // [8][128] f32 overlay (PHi dead)
    float* mlds = (float*)(smem + 34304);       // 64 f32
    float* slds = (float*)(smem + 34560);       // 64 f32 (1/rowsum)
    float* cw1  = (float*)(smem + 34816);       // 64 f32
    float* qw2e = (float*)(smem + 35072);       // 128 f32
    float* dred = (float*)(smem + 35584);       // 8 f32

    int b, cch;
    swz(blockIdx.y * 32 + blockIdx.x, b, cch);
    const int c0  = cch * CT;
    const int tid = threadIdx.x;
    const int lane = tid & 63;
    const int wv   = tid >> 6;
    const int w16  = wv * 16;
    const int lm   = lane & 15;
    const int lg   = lane >> 4;    // 0..3
    const int lk   = lg * 8;       // k-slot start within 32-chunk

    const float* ctxb = ctx + ((size_t)b * C_ + c0) * D_;
    const unsigned short* qw3Hb = qw3Hi + (size_t)b * Q_ * D_;
    const unsigned short* qTHb  = qTHi + (size_t)b * Q_ * D_;

    // one-shot: DMA ALL FOUR qw3 chunks now (8 global_load_lds per wave)
    #pragma unroll
    for (int t = 0; t < 4; ++t)
        stage_b(qw3Hb, t * 32, SB + t * 4096, wv, lane);

    if (tid < Q_) qw2e[tid] = qw2e_g[b * Q_ + tid];

    // A-preload (ctx rows, exact hi/lo split) with fused cw1 = ctx_row . w1
    const float* arow = ctxb + (size_t)(w16 + lm) * D_;
    bf16x8 aHr[4], aLr[4];
    float cws = 0.f;
    #pragma unroll
    for (int t = 0; t < 4; ++t) {
        float4 v0 = *(const float4*)(arow + t * 32 + lk);
        float4 v1 = *(const float4*)(arow + t * 32 + lk + 4);
        float4 w0 = *(const float4*)(w + t * 32 + lk);
        float4 w1v = *(const float4*)(w + t * 32 + lk + 4);
        cws += v0.x*w0.x + v0.y*w0.y + v0.z*w0.z + v0.w*w0.w
             + v1.x*w1v.x + v1.y*w1v.y + v1.z*w1v.z + v1.w*w1v.w;
        float vv[8] = {v0.x, v0.y, v0.z, v0.w, v1.x, v1.y, v1.z, v1.w};
        #pragma unroll
        for (int i = 0; i < 8; ++i) {
            short hh, ll; split_f32(vv[i], hh, ll);
            aHr[t][i] = hh; aLr[t][i] = ll;
        }
    }
    cws += __shfl_xor(cws, 16, 64);
    cws += __shfl_xor(cws, 32, 64);
    if (lane < 16) cw1[w16 + lm] = cws;

    // G2 A-fragments hoisted pre-barrier: G1 + softmax cover their latency
    bf16x8 qa[2][4];
    #pragma unroll
    for (int ds = 0; ds < 2; ++ds)
        #pragma unroll
        for (int t = 0; t < 4; ++t)
            qa[ds][t] = *(const bf16x8*)(qTHb + (size_t)(ds * 64 + w16 + lm) * 128 + t * 32 + lk);

    __syncthreads();   // single drain: 4 stage chunks + cw1/qw2e visible

    float qe[8];
    #pragma unroll
    for (int f = 0; f < 8; ++f) qe[f] = qw2e[f * 16 + lm];
    float cwr[4];
    #pragma unroll
    for (int r = 0; r < 4; ++r) cwr[r] = cw1[w16 + lg * 4 + r];

    const f32x4 vzero = {0.f, 0.f, 0.f, 0.f};
    f32x4 acc[8];
    #pragma unroll
    for (int f = 0; f < 8; ++f) acc[f] = vzero;

    // ---- GEMM1: S[c][q]; 64 MFMA, zero internal barriers
    #pragma unroll
    for (int t = 0; t < 4; ++t) {
        const short* sb = SB + t * 4096;
        bf16x8 aH = aHr[t], aL = aLr[t];
        #pragma unroll
        for (int f = 0; f < 8; ++f) {
            bf16x8 bH = *(const bf16x8*)(sb + (f * 16 + lm) * 32 + lk);
            acc[f] = __builtin_amdgcn_mfma_f32_16x16x32_bf16(aH, bH, acc[f], 0, 0, 0);
            acc[f] = __builtin_amdgcn_mfma_f32_16x16x32_bf16(aL, bH, acc[f], 0, 0, 0);
        }
    }
    __syncthreads();   // all stage reads done before PHi overlay

    // ---- softmax over q; P -> PHi bf16 rne; m,1/s -> LDS
    #pragma unroll
    for (int r = 0; r < 4; ++r) {
        float sv[8];
        float mx = -3.0e38f;
        #pragma unroll
        for (int f = 0; f < 8; ++f) {
            sv[f] = acc[f][r] + qe[f];
            mx = fmaxf(mx, sv[f]);
        }
        mx = fmaxf(mx, __shfl_xor(mx, 1, 16));
        mx = fmaxf(mx, __shfl_xor(mx, 2, 16));
        mx = fmaxf(mx, __shfl_xor(mx, 4, 16));
        mx = fmaxf(mx, __shfl_xor(mx, 8, 16));
        int lrow = w16 + lg * 4 + r;
        float s = 0.f;
        #pragma unroll
        for (int f = 0; f < 8; ++f) {
            float p = __expf(sv[f] - mx);
            s += p;
            PHi[lrow * 136 + f * 16 + lm] = bf16_rne(p);
        }
        s += __shfl_xor(s, 1, 16);
        s += __shfl_xor(s, 2, 16);
        s += __shfl_xor(s, 4, 16);
        s += __shfl_xor(s, 8, 16);
        if (lm == 0) { mlds[lrow] = mx + cwr[r]; slds[lrow] = 1.0f / s; }
    }
    __syncthreads();   // P + scalars visible to all waves

    // ---- G2 split per column-pair, interleaved with epilogue store passes
    const int rsel = tid >> 5;            // 0..7
    const int dd   = (tid & 31) * 4;      // 0..124
    float4 qacc = {0.f, 0.f, 0.f, 0.f};
    float denp = 0.f;
    #pragma unroll
    for (int p = 0; p < 2; ++p) {
        // G2 half: c2qT[d][c] for c in [p*32, p*32+32)
        f32x4 acc2[2][2];
        #pragma unroll
        for (int ds = 0; ds < 2; ++ds)
            #pragma unroll
            for (int fq = 0; fq < 2; ++fq) acc2[ds][fq] = vzero;
        #pragma unroll
        for (int t = 0; t < 4; ++t) {
            #pragma unroll
            for (int fq = 0; fq < 2; ++fq) {
                bf16x8 bP = *(const bf16x8*)(PHi + ((2*p+fq) * 16 + lm) * 136 + t * 32 + lk);
                acc2[0][fq] = __builtin_amdgcn_mfma_f32_16x16x32_bf16(qa[0][t], bP, acc2[0][fq], 0, 0, 0);
                acc2[1][fq] = __builtin_amdgcn_mfma_f32_16x16x32_bf16(qa[1][t], bP, acc2[1][fq], 0, 0, 0);
            }
        }
        // transpose write: lane owns c = (2p+fq)*16+lm, d = ds*64+w16+lg*4+r
        #pragma unroll
        for (int fq = 0; fq < 2; ++fq) {
            float ic = slds[(2*p+fq) * 16 + lm];
            int cl = fq * 16 + lm;
            #pragma unroll
            for (int ds = 0; ds < 2; ++ds) {
                f32x4 v = acc2[ds][fq];
                float4 o;
                o.x = v[0] * ic; o.y = v[1] * ic; o.z = v[2] * ic; o.w = v[3] * ic;
                *(float4*)(Tr + cl * 132 + ds * 64 + w16 + lg * 4) = o;
            }
        }
        __syncthreads();
        #pragma unroll
        for (int i = 0; i < 4; ++i) {
            int cl  = i * 8 + rsel;        // 0..31
            int row = p * 32 + cl;
            float4 a  = *(const float4*)(Tr + cl * 132 + dd);
            float4 cv = *(const float4*)(ctxb + (size_t)row * D_ + dd);
            float wgt = __expf(mlds[row] - OFF_);
            size_t obase = ((size_t)b * C_ + c0 + row) * (4 * D_);
            float4 pr;
            pr.x = cv.x*a.x; pr.y = cv.y*a.y; pr.z = cv.z*a.z; pr.w = cv.w*a.w;
            *(float4*)(out + obase + dd)          = cv;
            *(float4*)(out + obase + D_ + dd)     = a;
            *(float4*)(out + obase + 2 * D_ + dd) = pr;
            qacc.x += wgt * cv.x; qacc.y += wgt * cv.y;
            qacc.z += wgt * cv.z; qacc.w += wgt * cv.w;
            denp += wgt;
        }
        __syncthreads();   // Tr reads done before next pass overwrites
    }

    // ---- block q2c partial reduce (red overlays PHi region; PHi dead)
    *(float4*)(red + rsel * 128 + dd) = qacc;
    if ((tid & 31) == 0) dred[rsel] = denp;
    __syncthreads();
    if (tid < 128) {
        float s = 0.f;
        #pragma unroll
        for (int rr = 0; rr < 8; ++rr) s += red[rr * 128 + tid];
        part[((size_t)b * 32 + cch) * 128 + tid] = s;
    }
    if (tid == 0) {
        float s = 0.f;
        #pragma unroll
        for (int rr = 0; rr < 8; ++rr) s += dred[rr];
        denp_g[b * 32 + cch] = s;
    }
}

// ---------------- out4 (+fused q2c reduce): slice 3 = ctx * q2c ----------------
__global__ __launch_bounds__(256)
void cqa_out4(const float* __restrict__ ctx, const float* __restrict__ part,
              const float* __restrict__ denp_g, float* __restrict__ out)
{
    int b, ch;
    swz(blockIdx.y * 32 + blockIdx.x, b, ch);   // same XCD mapping as main
    const int tid = threadIdx.x;
    __shared__ float q2s[128];

    float den = 0.f;
    #pragma unroll 8
    for (int j = 0; j < 32; ++j) den += denp_g[b * 32 + j];
    if (tid < 128) {
        float s = 0.f;
        #pragma unroll 8
        for (int j = 0; j < 32; ++j) s += part[((size_t)b * 32 + j) * 128 + tid];
        q2s[tid] = s / den;
    }
    __syncthreads();

    const float* cb = ctx + ((size_t)b * C_ + ch * 64) * D_;
    float* ob = out + ((size_t)b * C_ + ch * 64) * (4 * D_);
    #pragma unroll
    for (int k = 0; k < 8; ++k) {
        int i  = tid + k * 256;          // 0..2047
        int rl = i >> 5, d4 = (i & 31) * 4;
        float4 c4 = *(const float4*)(cb + (size_t)rl * D_ + d4);
        float4 g4 = *(const float4*)(q2s + d4);
        float4 o;
        o.x = c4.x*g4.x; o.y = c4.y*g4.y; o.z = c4.z*g4.z; o.w = c4.w*g4.w;
        *(float4*)(ob + (size_t)rl * (4 * D_) + 3 * D_ + d4) = o;
    }
}

extern "C" void kernel_launch(void* const* d_in, const int* in_sizes, int n_in,
                              void* d_out, int out_size, void* d_ws, size_t ws_size,
                              hipStream_t stream)
{
    const float* ctx   = (const float*)d_in[0];
    const float* qry   = (const float*)d_in[1];
    const float* w     = (const float*)d_in[2];
    const int*   qmask = (const int*)d_in[3];
    float* out = (float*)d_out;
    float* ws  = (float*)d_ws;

    float* part    = ws;                        // B*32*128 = 131072 f32
    float* denp_g  = ws + 131072;               // 1024
    float* qw2e_g  = ws + 132096;               // 4096
    unsigned short* bf = (unsigned short*)(ws + 136192);
    unsigned short* qw3Hi = bf;                 // 524288 shorts
    unsigned short* qTHi  = bf + 524288;        // 524288 shorts

    cqa_prep<<<dim3(8, B_), 256, 0, stream>>>(qry, w, qmask, qw2e_g, qw3Hi, qTHi);
    cqa_main<<<dim3(C_/CT, B_), 256, 0, stream>>>(ctx, w, qw2e_g, qw3Hi, qTHi,
                                                  out, part, denp_g);
    cqa_out4<<<dim3(C_/64, B_), 256, 0, stream>>>(ctx, part, denp_g, out);
}